// Round 1
// baseline (559.885 us; speedup 1.0000x reference)
//
#include <hip/hip_runtime.h>
#include <hip/hip_bf16.h>

// Continuous-filter convolution (SchNet-style), MI355X gfx950.
// Sizes fixed by the reference problem:
#define HIDDEN 256
#define NB 128          // num RBF bases
#define TE 64           // edges per workgroup
#define E_TOTAL 262144
#define V_TOTAL 32768

typedef __attribute__((ext_vector_type(8))) __bf16 bf16x8;
typedef __attribute__((ext_vector_type(4))) float floatx4;
typedef __attribute__((ext_vector_type(4))) unsigned int uintx4;

__device__ inline unsigned short f2bf(float f) {
    union { float f; unsigned u; } v; v.f = f;
    unsigned r = v.u + 0x7fffu + ((v.u >> 16) & 1u);   // RNE
    return (unsigned short)(r >> 16);
}

// Transpose + bf16-convert the weights once per launch into workspace:
//   W1T[c][k] = bf16(W1[k][c])   c<256, k<128   (32768 elems)
//   W2T[c][k] = bf16(W2[k][c])   c<256, k<256   (65536 elems, offset 32768)
__global__ void cfconv_prep(const float* __restrict__ W1,
                            const float* __restrict__ W2,
                            unsigned short* __restrict__ wbuf) {
    int id = blockIdx.x * 256 + threadIdx.x;
    if (id < NB * HIDDEN) {
        int c = id >> 7, k = id & (NB - 1);
        wbuf[id] = f2bf(W1[k * HIDDEN + c]);
    }
    int id2 = id - NB * HIDDEN;
    if (id2 >= 0 && id2 < HIDDEN * HIDDEN) {
        int c = id2 >> 8, k = id2 & (HIDDEN - 1);
        wbuf[NB * HIDDEN + id2] = f2bf(W2[k * HIDDEN + c]);
    }
}

// Fused: D -> rbf -> (rbf@W1,relu) -> (h@W2,relu) -> *X[src] -> atomic add H[dest]
// Block = 256 threads (4 waves). Each block owns 64 consecutive edges.
// Wave w owns output columns [64w, 64w+64).
__global__ __launch_bounds__(256)
void cfconv_main(const float* __restrict__ X,
                 const float* __restrict__ R,
                 const unsigned short* __restrict__ W1T,
                 const unsigned short* __restrict__ W2T,
                 const float* __restrict__ mu,
                 const int* __restrict__ src,
                 const int* __restrict__ dest,
                 float* __restrict__ out) {
    __shared__ float Dlds[TE];
    __shared__ float mulds[NB];
    __shared__ __align__(16) unsigned short rbf_lds[TE * NB];     // 16 KB, swizzled
    __shared__ __align__(16) unsigned short h_lds[TE * HIDDEN];   // 32 KB, swizzled

    const int t = threadIdx.x;
    const int eb = blockIdx.x * TE;

    // ---- Phase 0: per-edge squared distance + mu into LDS ----
    if (t < NB) mulds[t] = mu[t];
    if (t < TE) {
        int e = eb + t;
        int s = src[e], d = dest[e];
        float dx = R[s * 3 + 0] - R[d * 3 + 0];
        float dy = R[s * 3 + 1] - R[d * 3 + 1];
        float dz = R[s * 3 + 2] - R[d * 3 + 2];
        Dlds[t] = dx * dx + dy * dy + dz * dz;
    }
    __syncthreads();

    // ---- Phase 1: rbf tile [64][128] bf16 into LDS (XOR-swizzled rows) ----
    {
        float dm = mulds[1] - mulds[0];
        float gamma = 1.0f / (dm * dm);
        int e = t >> 2;                  // 0..63
        int b0 = (t & 3) * 32;           // 4 threads per row, 32 bases each
        float D = Dlds[e];
        char* rb = (char*)rbf_lds;
        int swz = (e & 7) << 4;
        for (int g = 0; g < 4; ++g) {
            int b = b0 + g * 8;
            unsigned short v[8];
            #pragma unroll
            for (int j = 0; j < 8; ++j) {
                float d = D - mulds[b + j];
                v[j] = f2bf(__expf(-gamma * d * d));
            }
            uintx4 pack;
            pack.x = (unsigned)v[0] | ((unsigned)v[1] << 16);
            pack.y = (unsigned)v[2] | ((unsigned)v[3] << 16);
            pack.z = (unsigned)v[4] | ((unsigned)v[5] << 16);
            pack.w = (unsigned)v[6] | ((unsigned)v[7] << 16);
            int byteoff = e * (NB * 2) + ((b * 2) ^ swz);
            *(uintx4*)(rb + byteoff) = pack;
        }
    }
    __syncthreads();

    const int lane = t & 63;
    const int w = t >> 6;        // wave id 0..3
    const int lhi = lane >> 4;   // 0..3
    const int llo = lane & 15;   // 0..15

    // ---- Phase 2: h = relu(rbf @ W1) -> LDS bf16 [64][256] swizzled ----
    {
        floatx4 acc[4][4];
        #pragma unroll
        for (int m = 0; m < 4; ++m)
            #pragma unroll
            for (int n = 0; n < 4; ++n)
                acc[m][n] = (floatx4)(0.0f);

        const char* rb = (const char*)rbf_lds;
        #pragma unroll
        for (int kc = 0; kc < 4; ++kc) {     // K = 128 in chunks of 32
            bf16x8 a[4], b[4];
            #pragma unroll
            for (int m = 0; m < 4; ++m) {
                int row = 16 * m + llo;
                int byteoff = row * (NB * 2) + ((kc * 64 + 16 * lhi) ^ ((row & 7) << 4));
                a[m] = *(const bf16x8*)(rb + byteoff);
            }
            #pragma unroll
            for (int n = 0; n < 4; ++n) {
                int col = w * 64 + 16 * n + llo;
                b[n] = *(const bf16x8*)(W1T + col * NB + kc * 32 + lhi * 8);
            }
            #pragma unroll
            for (int m = 0; m < 4; ++m)
                #pragma unroll
                for (int n = 0; n < 4; ++n)
                    acc[m][n] = __builtin_amdgcn_mfma_f32_16x16x32_bf16(a[m], b[n], acc[m][n], 0, 0, 0);
        }

        // write h (relu) to LDS bf16, swizzled rows (stride 512B)
        char* hb = (char*)h_lds;
        #pragma unroll
        for (int m = 0; m < 4; ++m) {
            #pragma unroll
            for (int n = 0; n < 4; ++n) {
                int col = w * 64 + 16 * n + llo;
                #pragma unroll
                for (int r = 0; r < 4; ++r) {
                    int row = 16 * m + 4 * lhi + r;
                    float v = fmaxf(acc[m][n][r], 0.0f);
                    int byteoff = row * (HIDDEN * 2) + ((col * 2) ^ ((row & 7) << 4));
                    *(unsigned short*)(hb + byteoff) = f2bf(v);
                }
            }
        }
    }
    __syncthreads();

    // ---- Phase 3: M = relu(h @ W2), fused epilogue ----
    {
        floatx4 acc[4][4];
        #pragma unroll
        for (int m = 0; m < 4; ++m)
            #pragma unroll
            for (int n = 0; n < 4; ++n)
                acc[m][n] = (floatx4)(0.0f);

        const char* hb = (const char*)h_lds;
        #pragma unroll
        for (int kc = 0; kc < 8; ++kc) {     // K = 256 in chunks of 32
            bf16x8 a[4], b[4];
            #pragma unroll
            for (int m = 0; m < 4; ++m) {
                int row = 16 * m + llo;
                int byteoff = row * (HIDDEN * 2) + ((kc * 64 + 16 * lhi) ^ ((row & 7) << 4));
                a[m] = *(const bf16x8*)(hb + byteoff);
            }
            #pragma unroll
            for (int n = 0; n < 4; ++n) {
                int col = w * 64 + 16 * n + llo;
                b[n] = *(const bf16x8*)(W2T + col * HIDDEN + kc * 32 + lhi * 8);
            }
            #pragma unroll
            for (int m = 0; m < 4; ++m)
                #pragma unroll
                for (int n = 0; n < 4; ++n)
                    acc[m][n] = __builtin_amdgcn_mfma_f32_16x16x32_bf16(a[m], b[n], acc[m][n], 0, 0, 0);
        }

        // epilogue: msg = X[src] * relu(M);  atomicAdd into out[dest]
        #pragma unroll
        for (int m = 0; m < 4; ++m) {
            #pragma unroll
            for (int r = 0; r < 4; ++r) {
                int row = 16 * m + 4 * lhi + r;
                int e = eb + row;
                int s = src[e];
                int d = dest[e];
                const float* xr = X + (long)s * HIDDEN;
                float* orow = out + (long)d * HIDDEN;
                #pragma unroll
                for (int n = 0; n < 4; ++n) {
                    int c = w * 64 + 16 * n + llo;
                    float v = fmaxf(acc[m][n][r], 0.0f) * xr[c];
                    unsafeAtomicAdd(&orow[c], v);
                }
            }
        }
    }
}

extern "C" void kernel_launch(void* const* d_in, const int* in_sizes, int n_in,
                              void* d_out, int out_size, void* d_ws, size_t ws_size,
                              hipStream_t stream) {
    const float* X  = (const float*)d_in[0];
    const float* R  = (const float*)d_in[1];
    const float* W1 = (const float*)d_in[2];
    const float* W2 = (const float*)d_in[3];
    const float* mu = (const float*)d_in[4];
    const int* src  = (const int*)d_in[5];
    const int* dest = (const int*)d_in[6];
    float* out = (float*)d_out;

    unsigned short* W1T = (unsigned short*)d_ws;            // 32768 bf16
    unsigned short* W2T = W1T + NB * HIDDEN;                // 65536 bf16

    hipMemsetAsync(d_out, 0, (size_t)out_size * sizeof(float), stream);

    cfconv_prep<<<(NB * HIDDEN + HIDDEN * HIDDEN + 255) / 256, 256, 0, stream>>>(W1, W2, W1T);

    cfconv_main<<<E_TOTAL / TE, 256, 0, stream>>>(X, R, W1T, W2T, mu, src, dest, out);
}

// Round 2
// 262.948 us; speedup vs baseline: 2.1293x; 2.1293x over previous
//
#include <hip/hip_runtime.h>
#include <hip/hip_bf16.h>

// Continuous-filter convolution (SchNet-style), MI355X gfx950.
#define HIDDEN 256
#define NB 128          // num RBF bases
#define TE 64           // edges per workgroup
#define E_TOTAL 262144
#define V_TOTAL 32768

typedef __attribute__((ext_vector_type(8))) __bf16 bf16x8;
typedef __attribute__((ext_vector_type(4))) float floatx4;
typedef __attribute__((ext_vector_type(4))) unsigned int uintx4;

__device__ inline unsigned short f2bf(float f) {
    union { float f; unsigned u; } v; v.f = f;
    unsigned r = v.u + 0x7fffu + ((v.u >> 16) & 1u);   // RNE
    return (unsigned short)(r >> 16);
}

// Transpose + bf16-convert the weights once per launch into workspace:
//   W1T[c][k] = bf16(W1[k][c])   c<256, k<128   (32768 elems)
//   W2T[c][k] = bf16(W2[k][c])   c<256, k<256   (65536 elems, offset 32768)
__global__ void cfconv_prep(const float* __restrict__ W1,
                            const float* __restrict__ W2,
                            unsigned short* __restrict__ wbuf) {
    int id = blockIdx.x * 256 + threadIdx.x;
    if (id < NB * HIDDEN) {
        int c = id >> 7, k = id & (NB - 1);
        wbuf[id] = f2bf(W1[k * HIDDEN + c]);
    }
    int id2 = id - NB * HIDDEN;
    if (id2 >= 0 && id2 < HIDDEN * HIDDEN) {
        int c = id2 >> 8, k = id2 & (HIDDEN - 1);
        wbuf[NB * HIDDEN + id2] = f2bf(W2[k * HIDDEN + c]);
    }
}

// Fused: D -> rbf -> (rbf@W1,relu) -> (h@W2,relu) -> *X[src] -> run-length
// reduced atomic add into H[dest]. Block = 256 threads (4 waves), 64 edges.
__global__ __launch_bounds__(256)
void cfconv_main(const float* __restrict__ X,
                 const float* __restrict__ R,
                 const unsigned short* __restrict__ W1T,
                 const unsigned short* __restrict__ W2T,
                 const float* __restrict__ mu,
                 const int* __restrict__ src,
                 const int* __restrict__ dest,
                 float* __restrict__ out) {
    __shared__ float Dlds[TE];
    __shared__ int srcl[TE];
    __shared__ int destl[TE];
    __shared__ float mulds[NB];
    __shared__ __align__(16) unsigned short rbf_lds[TE * NB];     // 16 KB, swizzled
    __shared__ __align__(16) unsigned short h_lds[TE * HIDDEN];   // 32 KB, swizzled; reused for M

    const int t = threadIdx.x;
    const int eb = blockIdx.x * TE;

    // ---- Phase 0: edge meta + squared distance into LDS ----
    if (t < NB) mulds[t] = mu[t];
    if (t < TE) {
        int e = eb + t;
        int s = src[e], d = dest[e];
        srcl[t] = s;
        destl[t] = d;
        float dx = R[s * 3 + 0] - R[d * 3 + 0];
        float dy = R[s * 3 + 1] - R[d * 3 + 1];
        float dz = R[s * 3 + 2] - R[d * 3 + 2];
        Dlds[t] = dx * dx + dy * dy + dz * dz;
    }
    __syncthreads();

    // ---- Phase 1: rbf tile [64][128] bf16 into LDS (XOR-swizzled rows) ----
    {
        float dm = mulds[1] - mulds[0];
        float gamma = 1.0f / (dm * dm);
        int e = t >> 2;                  // 0..63
        int b0 = (t & 3) * 32;           // 4 threads per row, 32 bases each
        float D = Dlds[e];
        char* rb = (char*)rbf_lds;
        int swz = (e & 7) << 4;
        for (int g = 0; g < 4; ++g) {
            int b = b0 + g * 8;
            unsigned short v[8];
            #pragma unroll
            for (int j = 0; j < 8; ++j) {
                float d = D - mulds[b + j];
                v[j] = f2bf(__expf(-gamma * d * d));
            }
            uintx4 pack;
            pack.x = (unsigned)v[0] | ((unsigned)v[1] << 16);
            pack.y = (unsigned)v[2] | ((unsigned)v[3] << 16);
            pack.z = (unsigned)v[4] | ((unsigned)v[5] << 16);
            pack.w = (unsigned)v[6] | ((unsigned)v[7] << 16);
            int byteoff = e * (NB * 2) + ((b * 2) ^ swz);
            *(uintx4*)(rb + byteoff) = pack;
        }
    }
    __syncthreads();

    const int lane = t & 63;
    const int w = t >> 6;        // wave id 0..3
    const int lhi = lane >> 4;   // 0..3
    const int llo = lane & 15;   // 0..15

    // ---- Phase 2: h = relu(rbf @ W1) -> LDS bf16 [64][256] swizzled ----
    {
        floatx4 acc[4][4];
        #pragma unroll
        for (int m = 0; m < 4; ++m)
            #pragma unroll
            for (int n = 0; n < 4; ++n)
                acc[m][n] = (floatx4)(0.0f);

        const char* rb = (const char*)rbf_lds;
        #pragma unroll
        for (int kc = 0; kc < 4; ++kc) {     // K = 128 in chunks of 32
            bf16x8 a[4], b[4];
            #pragma unroll
            for (int m = 0; m < 4; ++m) {
                int row = 16 * m + llo;
                int byteoff = row * (NB * 2) + ((kc * 64 + 16 * lhi) ^ ((row & 7) << 4));
                a[m] = *(const bf16x8*)(rb + byteoff);
            }
            #pragma unroll
            for (int n = 0; n < 4; ++n) {
                int col = w * 64 + 16 * n + llo;
                b[n] = *(const bf16x8*)(W1T + col * NB + kc * 32 + lhi * 8);
            }
            #pragma unroll
            for (int m = 0; m < 4; ++m)
                #pragma unroll
                for (int n = 0; n < 4; ++n)
                    acc[m][n] = __builtin_amdgcn_mfma_f32_16x16x32_bf16(a[m], b[n], acc[m][n], 0, 0, 0);
        }

        // write h (relu) to LDS bf16, swizzled rows (stride 512B)
        char* hb = (char*)h_lds;
        #pragma unroll
        for (int m = 0; m < 4; ++m) {
            #pragma unroll
            for (int n = 0; n < 4; ++n) {
                int col = w * 64 + 16 * n + llo;
                #pragma unroll
                for (int r = 0; r < 4; ++r) {
                    int row = 16 * m + 4 * lhi + r;
                    float v = fmaxf(acc[m][n][r], 0.0f);
                    int byteoff = row * (HIDDEN * 2) + ((col * 2) ^ ((row & 7) << 4));
                    *(unsigned short*)(hb + byteoff) = f2bf(v);
                }
            }
        }
    }
    __syncthreads();

    // ---- Phase 3: M = relu(h @ W2) ----
    floatx4 acc[4][4];
    {
        #pragma unroll
        for (int m = 0; m < 4; ++m)
            #pragma unroll
            for (int n = 0; n < 4; ++n)
                acc[m][n] = (floatx4)(0.0f);

        const char* hb = (const char*)h_lds;
        #pragma unroll
        for (int kc = 0; kc < 8; ++kc) {     // K = 256 in chunks of 32
            bf16x8 a[4], b[4];
            #pragma unroll
            for (int m = 0; m < 4; ++m) {
                int row = 16 * m + llo;
                int byteoff = row * (HIDDEN * 2) + ((kc * 64 + 16 * lhi) ^ ((row & 7) << 4));
                a[m] = *(const bf16x8*)(hb + byteoff);
            }
            #pragma unroll
            for (int n = 0; n < 4; ++n) {
                int col = w * 64 + 16 * n + llo;
                b[n] = *(const bf16x8*)(W2T + col * HIDDEN + kc * 32 + lhi * 8);
            }
            #pragma unroll
            for (int m = 0; m < 4; ++m)
                #pragma unroll
                for (int n = 0; n < 4; ++n)
                    acc[m][n] = __builtin_amdgcn_mfma_f32_16x16x32_bf16(a[m], b[n], acc[m][n], 0, 0, 0);
        }
    }
    __syncthreads();   // everyone done READING h_lds before we overwrite with M

    // ---- Phase 4: store relu(M) bf16 into h_lds (same swizzle) ----
    {
        char* hb = (char*)h_lds;
        #pragma unroll
        for (int m = 0; m < 4; ++m) {
            #pragma unroll
            for (int n = 0; n < 4; ++n) {
                int col = w * 64 + 16 * n + llo;
                #pragma unroll
                for (int r = 0; r < 4; ++r) {
                    int row = 16 * m + 4 * lhi + r;
                    float v = fmaxf(acc[m][n][r], 0.0f);
                    int byteoff = row * (HIDDEN * 2) + ((col * 2) ^ ((row & 7) << 4));
                    *(unsigned short*)(hb + byteoff) = f2bf(v);
                }
            }
        }
    }
    __syncthreads();

    // ---- Phase 5: per-column run-length segmented scatter ----
    // Thread t owns output column c=t. Walk the 64 (dest-sorted) edges,
    // accumulate while dest unchanged, flush one distinct-address atomic/run.
    {
        const char* hb = (const char*)h_lds;
        const int c = t;
        float racc = 0.0f;
        int dprev = __builtin_amdgcn_readfirstlane(destl[0]);
        #pragma unroll 8
        for (int r = 0; r < TE; ++r) {
            int d = __builtin_amdgcn_readfirstlane(destl[r]);
            int s = __builtin_amdgcn_readfirstlane(srcl[r]);
            unsigned short m16 = *(const unsigned short*)(hb + r * (HIDDEN * 2) + ((2 * c) ^ ((r & 7) << 4)));
            union { unsigned u; float f; } cv; cv.u = ((unsigned)m16) << 16;
            float x = X[(long)s * HIDDEN + c];
            if (d != dprev) {
                unsafeAtomicAdd(out + (long)dprev * HIDDEN + c, racc);
                racc = 0.0f;
                dprev = d;
            }
            racc += cv.f * x;
        }
        unsafeAtomicAdd(out + (long)dprev * HIDDEN + c, racc);
    }
}

extern "C" void kernel_launch(void* const* d_in, const int* in_sizes, int n_in,
                              void* d_out, int out_size, void* d_ws, size_t ws_size,
                              hipStream_t stream) {
    const float* X  = (const float*)d_in[0];
    const float* R  = (const float*)d_in[1];
    const float* W1 = (const float*)d_in[2];
    const float* W2 = (const float*)d_in[3];
    const float* mu = (const float*)d_in[4];
    const int* src  = (const int*)d_in[5];
    const int* dest = (const int*)d_in[6];
    float* out = (float*)d_out;

    unsigned short* W1T = (unsigned short*)d_ws;            // 32768 bf16
    unsigned short* W2T = W1T + NB * HIDDEN;                // 65536 bf16

    hipMemsetAsync(d_out, 0, (size_t)out_size * sizeof(float), stream);

    cfconv_prep<<<(NB * HIDDEN + HIDDEN * HIDDEN + 255) / 256, 256, 0, stream>>>(W1, W2, W1T);

    cfconv_main<<<E_TOTAL / TE, 256, 0, stream>>>(X, R, W1T, W2T, mu, src, dest, out);
}

// Round 3
// 191.463 us; speedup vs baseline: 2.9242x; 1.3734x over previous
//
#include <hip/hip_runtime.h>
#include <hip/hip_bf16.h>

// Continuous-filter convolution (SchNet-style), MI355X gfx950.
#define HIDDEN 256
#define NB 128          // num RBF bases
#define TE 64           // edges per workgroup
#define E_TOTAL 262144
#define V_TOTAL 32768

typedef __attribute__((ext_vector_type(8))) __bf16 bf16x8;
typedef __attribute__((ext_vector_type(4))) float floatx4;

__device__ inline unsigned short f2bf(float f) {
    union { float f; unsigned u; } v; v.f = f;
    unsigned r = v.u + 0x7fffu + ((v.u >> 16) & 1u);   // RNE
    return (unsigned short)(r >> 16);
}

// Transpose + bf16-convert the weights once per launch into workspace:
//   W1T[c][k] = bf16(W1[k][c])   c<256, k<128   (32768 elems)
//   W2T[c][k] = bf16(W2[k][c])   c<256, k<256   (65536 elems, offset 32768)
__global__ void cfconv_prep(const float* __restrict__ W1,
                            const float* __restrict__ W2,
                            unsigned short* __restrict__ wbuf) {
    int id = blockIdx.x * 256 + threadIdx.x;
    if (id < NB * HIDDEN) {
        int c = id >> 7, k = id & (NB - 1);
        wbuf[id] = f2bf(W1[k * HIDDEN + c]);
    }
    int id2 = id - NB * HIDDEN;
    if (id2 >= 0 && id2 < HIDDEN * HIDDEN) {
        int c = id2 >> 8, k = id2 & (HIDDEN - 1);
        wbuf[NB * HIDDEN + id2] = f2bf(W2[k * HIDDEN + c]);
    }
}

// Fused: D -> rbf(in-register) -> (rbf@W1,relu) -> (h@W2,relu) -> *X[src]
// -> run-length reduced atomic add into H[dest].
// Block = 256 threads (4 waves), 64 edges. LDS ~34 KB -> 4 blocks/CU.
__global__ __launch_bounds__(256, 4)
void cfconv_main(const float* __restrict__ X,
                 const float* __restrict__ R,
                 const unsigned short* __restrict__ W1T,
                 const unsigned short* __restrict__ W2T,
                 const float* __restrict__ mu,
                 const int* __restrict__ src,
                 const int* __restrict__ dest,
                 float* __restrict__ out) {
    __shared__ __align__(16) float Dlds[TE];
    __shared__ int srcl[TE];
    __shared__ int destl[TE];
    __shared__ __align__(16) float mulds[NB];
    __shared__ __align__(16) unsigned short h_lds[TE * HIDDEN];   // 32 KB, swizzled; h then M

    const int t = threadIdx.x;
    const int eb = blockIdx.x * TE;

    // ---- Phase 0: edge meta + squared distance into LDS ----
    if (t < NB) mulds[t] = mu[t];
    if (t < TE) {
        int e = eb + t;
        int s = src[e], d = dest[e];
        srcl[t] = s;
        destl[t] = d;
        float dx = R[s * 3 + 0] - R[d * 3 + 0];
        float dy = R[s * 3 + 1] - R[d * 3 + 1];
        float dz = R[s * 3 + 2] - R[d * 3 + 2];
        Dlds[t] = dx * dx + dy * dy + dz * dz;
    }
    __syncthreads();

    const int lane = t & 63;
    const int w = t >> 6;        // wave id 0..3
    const int lhi = lane >> 4;   // 0..3
    const int llo = lane & 15;   // 0..15

    // ---- Phase 1: h = relu(rbf @ W1), rbf A-fragments computed in-register ----
    {
        float dm = mulds[1] - mulds[0];
        float ng = -1.0f / (dm * dm);            // -gamma
        float Dm[4];
        #pragma unroll
        for (int m = 0; m < 4; ++m) Dm[m] = Dlds[16 * m + llo];

        floatx4 acc[4][4];
        #pragma unroll
        for (int m = 0; m < 4; ++m)
            #pragma unroll
            for (int n = 0; n < 4; ++n)
                acc[m][n] = (floatx4)(0.0f);

        #pragma unroll
        for (int kc = 0; kc < 4; ++kc) {     // K = 128 in chunks of 32
            // this lane's 8 mu values for k = kc*32 + lhi*8 + j
            floatx4 mu0 = *(const floatx4*)(mulds + kc * 32 + lhi * 8);
            floatx4 mu1 = *(const floatx4*)(mulds + kc * 32 + lhi * 8 + 4);
            bf16x8 a[4], b[4];
            #pragma unroll
            for (int m = 0; m < 4; ++m) {
                float D = Dm[m];
                #pragma unroll
                for (int j = 0; j < 8; ++j) {
                    float mv = (j < 4) ? mu0[j] : mu1[j - 4];
                    float d = D - mv;
                    a[m][j] = (__bf16)__expf(ng * d * d);
                }
            }
            #pragma unroll
            for (int n = 0; n < 4; ++n) {
                int col = w * 64 + 16 * n + llo;
                b[n] = *(const bf16x8*)(W1T + col * NB + kc * 32 + lhi * 8);
            }
            #pragma unroll
            for (int m = 0; m < 4; ++m)
                #pragma unroll
                for (int n = 0; n < 4; ++n)
                    acc[m][n] = __builtin_amdgcn_mfma_f32_16x16x32_bf16(a[m], b[n], acc[m][n], 0, 0, 0);
        }

        // write h (relu) to LDS bf16, swizzled rows (stride 512B)
        char* hb = (char*)h_lds;
        #pragma unroll
        for (int m = 0; m < 4; ++m) {
            #pragma unroll
            for (int n = 0; n < 4; ++n) {
                int col = w * 64 + 16 * n + llo;
                #pragma unroll
                for (int r = 0; r < 4; ++r) {
                    int row = 16 * m + 4 * lhi + r;
                    float v = fmaxf(acc[m][n][r], 0.0f);
                    int byteoff = row * (HIDDEN * 2) + ((col * 2) ^ ((row & 7) << 4));
                    *(__bf16*)(hb + byteoff) = (__bf16)v;
                }
            }
        }
    }
    __syncthreads();

    // ---- Phase 2: M = relu(h @ W2) ----
    floatx4 acc[4][4];
    {
        #pragma unroll
        for (int m = 0; m < 4; ++m)
            #pragma unroll
            for (int n = 0; n < 4; ++n)
                acc[m][n] = (floatx4)(0.0f);

        const char* hb = (const char*)h_lds;
        #pragma unroll
        for (int kc = 0; kc < 8; ++kc) {     // K = 256 in chunks of 32
            bf16x8 a[4], b[4];
            #pragma unroll
            for (int m = 0; m < 4; ++m) {
                int row = 16 * m + llo;
                int byteoff = row * (HIDDEN * 2) + ((kc * 64 + 16 * lhi) ^ ((row & 7) << 4));
                a[m] = *(const bf16x8*)(hb + byteoff);
            }
            #pragma unroll
            for (int n = 0; n < 4; ++n) {
                int col = w * 64 + 16 * n + llo;
                b[n] = *(const bf16x8*)(W2T + col * HIDDEN + kc * 32 + lhi * 8);
            }
            #pragma unroll
            for (int m = 0; m < 4; ++m)
                #pragma unroll
                for (int n = 0; n < 4; ++n)
                    acc[m][n] = __builtin_amdgcn_mfma_f32_16x16x32_bf16(a[m], b[n], acc[m][n], 0, 0, 0);
        }
    }
    __syncthreads();   // everyone done READING h_lds before we overwrite with M

    // ---- Phase 3: store relu(M) bf16 into h_lds (same swizzle) ----
    {
        char* hb = (char*)h_lds;
        #pragma unroll
        for (int m = 0; m < 4; ++m) {
            #pragma unroll
            for (int n = 0; n < 4; ++n) {
                int col = w * 64 + 16 * n + llo;
                #pragma unroll
                for (int r = 0; r < 4; ++r) {
                    int row = 16 * m + 4 * lhi + r;
                    float v = fmaxf(acc[m][n][r], 0.0f);
                    int byteoff = row * (HIDDEN * 2) + ((col * 2) ^ ((row & 7) << 4));
                    *(__bf16*)(hb + byteoff) = (__bf16)v;
                }
            }
        }
    }
    __syncthreads();

    // ---- Phase 4: per-column run-length segmented scatter ----
    // Thread t owns output column c=t. Walk the 64 (dest-sorted) edges,
    // accumulate while dest unchanged, flush one distinct-address atomic/run.
    {
        const char* hb = (const char*)h_lds;
        const int c = t;
        float racc = 0.0f;
        int dprev = __builtin_amdgcn_readfirstlane(destl[0]);
        #pragma unroll 8
        for (int r = 0; r < TE; ++r) {
            int d = __builtin_amdgcn_readfirstlane(destl[r]);
            int s = __builtin_amdgcn_readfirstlane(srcl[r]);
            unsigned short m16 = *(const unsigned short*)(hb + r * (HIDDEN * 2) + ((2 * c) ^ ((r & 7) << 4)));
            union { unsigned u; float f; } cv; cv.u = ((unsigned)m16) << 16;
            float x = X[(long)s * HIDDEN + c];
            if (d != dprev) {
                unsafeAtomicAdd(out + (long)dprev * HIDDEN + c, racc);
                racc = 0.0f;
                dprev = d;
            }
            racc += cv.f * x;
        }
        unsafeAtomicAdd(out + (long)dprev * HIDDEN + c, racc);
    }
}

extern "C" void kernel_launch(void* const* d_in, const int* in_sizes, int n_in,
                              void* d_out, int out_size, void* d_ws, size_t ws_size,
                              hipStream_t stream) {
    const float* X  = (const float*)d_in[0];
    const float* R  = (const float*)d_in[1];
    const float* W1 = (const float*)d_in[2];
    const float* W2 = (const float*)d_in[3];
    const float* mu = (const float*)d_in[4];
    const int* src  = (const int*)d_in[5];
    const int* dest = (const int*)d_in[6];
    float* out = (float*)d_out;

    unsigned short* W1T = (unsigned short*)d_ws;            // 32768 bf16
    unsigned short* W2T = W1T + NB * HIDDEN;                // 65536 bf16

    hipMemsetAsync(d_out, 0, (size_t)out_size * sizeof(float), stream);

    cfconv_prep<<<(NB * HIDDEN + HIDDEN * HIDDEN + 255) / 256, 256, 0, stream>>>(W1, W2, W1T);

    cfconv_main<<<E_TOTAL / TE, 256, 0, stream>>>(X, R, W1T, W2T, mu, src, dest, out);
}

// Round 4
// 80.494 us; speedup vs baseline: 6.9556x; 2.3786x over previous
//
#include <hip/hip_runtime.h>
#include <hip/hip_bf16.h>

// Continuous-filter convolution (SchNet-style), MI355X gfx950.
// Key fact: M_ij = relu(relu(rbf(D_ij)@W1)@W2) depends ONLY on the scalar
// squared-distance D_ij in [0, R^2). We build a T-point lookup table of
// F(D) on-device each launch (bf16 MFMA pipeline, same as the previously
// verified fused kernel), then the main kernel is a pure lerp+gather+scatter.
#define HIDDEN 256
#define NB 128          // num RBF bases
#define TE 64           // edges (or grid rows) per workgroup
#define E_TOTAL 262144
#define V_TOTAL 32768
#define R2MAX 2.25f

typedef __attribute__((ext_vector_type(8))) __bf16 bf16x8;
typedef __attribute__((ext_vector_type(4))) float floatx4;

__device__ inline unsigned short f2bf(float f) {
    union { float f; unsigned u; } v; v.f = f;
    unsigned r = v.u + 0x7fffu + ((v.u >> 16) & 1u);   // RNE
    return (unsigned short)(r >> 16);
}

// Transpose + bf16-convert the weights once per launch into workspace:
//   W1T[c][k] = bf16(W1[k][c])   c<256, k<128
//   W2T[c][k] = bf16(W2[k][c])   c<256, k<256
__global__ void cfconv_prep(const float* __restrict__ W1,
                            const float* __restrict__ W2,
                            unsigned short* __restrict__ wbuf) {
    int id = blockIdx.x * 256 + threadIdx.x;
    if (id < NB * HIDDEN) {
        int c = id >> 7, k = id & (NB - 1);
        wbuf[id] = f2bf(W1[k * HIDDEN + c]);
    }
    int id2 = id - NB * HIDDEN;
    if (id2 >= 0 && id2 < HIDDEN * HIDDEN) {
        int c = id2 >> 8, k = id2 & (HIDDEN - 1);
        wbuf[NB * HIDDEN + id2] = f2bf(W2[k * HIDDEN + c]);
    }
}

// Build the F(D) table at grid points D_i = i*invScale, i in [0,T).
// tab16 is a u16 view of u32 pair table: pair[i][c] = lo:M[i][c], hi:M[i+1][c].
// Row i writes lo of pair[i] and hi of pair[i-1].
__global__ __launch_bounds__(256, 4)
void cfconv_build(const unsigned short* __restrict__ W1T,
                  const unsigned short* __restrict__ W2T,
                  const float* __restrict__ mu,
                  unsigned short* __restrict__ tab16,
                  float invScale) {
    __shared__ __align__(16) float mulds[NB];
    __shared__ __align__(16) unsigned short h_lds[TE * HIDDEN];   // 32 KB swizzled; h then M

    const int t = threadIdx.x;
    const int eb = blockIdx.x * TE;          // first grid row of this block

    if (t < NB) mulds[t] = mu[t];
    __syncthreads();

    const int lane = t & 63;
    const int w = t >> 6;
    const int lhi = lane >> 4;
    const int llo = lane & 15;

    // ---- GEMM1: h = relu(rbf @ W1), rbf computed in-register from grid D ----
    {
        float dm = mulds[1] - mulds[0];
        float ng = -1.0f / (dm * dm);
        float Dm[4];
        #pragma unroll
        for (int m = 0; m < 4; ++m) Dm[m] = (float)(eb + 16 * m + llo) * invScale;

        floatx4 acc[4][4];
        #pragma unroll
        for (int m = 0; m < 4; ++m)
            #pragma unroll
            for (int n = 0; n < 4; ++n)
                acc[m][n] = (floatx4)(0.0f);

        #pragma unroll
        for (int kc = 0; kc < 4; ++kc) {
            floatx4 mu0 = *(const floatx4*)(mulds + kc * 32 + lhi * 8);
            floatx4 mu1 = *(const floatx4*)(mulds + kc * 32 + lhi * 8 + 4);
            bf16x8 a[4], b[4];
            #pragma unroll
            for (int m = 0; m < 4; ++m) {
                float D = Dm[m];
                #pragma unroll
                for (int j = 0; j < 8; ++j) {
                    float mv = (j < 4) ? mu0[j] : mu1[j - 4];
                    float d = D - mv;
                    a[m][j] = (__bf16)__expf(ng * d * d);
                }
            }
            #pragma unroll
            for (int n = 0; n < 4; ++n) {
                int col = w * 64 + 16 * n + llo;
                b[n] = *(const bf16x8*)(W1T + col * NB + kc * 32 + lhi * 8);
            }
            #pragma unroll
            for (int m = 0; m < 4; ++m)
                #pragma unroll
                for (int n = 0; n < 4; ++n)
                    acc[m][n] = __builtin_amdgcn_mfma_f32_16x16x32_bf16(a[m], b[n], acc[m][n], 0, 0, 0);
        }

        char* hb = (char*)h_lds;
        #pragma unroll
        for (int m = 0; m < 4; ++m)
            #pragma unroll
            for (int n = 0; n < 4; ++n) {
                int col = w * 64 + 16 * n + llo;
                #pragma unroll
                for (int r = 0; r < 4; ++r) {
                    int row = 16 * m + 4 * lhi + r;
                    float v = fmaxf(acc[m][n][r], 0.0f);
                    int byteoff = row * (HIDDEN * 2) + ((col * 2) ^ ((row & 7) << 4));
                    *(__bf16*)(hb + byteoff) = (__bf16)v;
                }
            }
    }
    __syncthreads();

    // ---- GEMM2: M = relu(h @ W2) ----
    floatx4 acc[4][4];
    {
        #pragma unroll
        for (int m = 0; m < 4; ++m)
            #pragma unroll
            for (int n = 0; n < 4; ++n)
                acc[m][n] = (floatx4)(0.0f);

        const char* hb = (const char*)h_lds;
        #pragma unroll
        for (int kc = 0; kc < 8; ++kc) {
            bf16x8 a[4], b[4];
            #pragma unroll
            for (int m = 0; m < 4; ++m) {
                int row = 16 * m + llo;
                int byteoff = row * (HIDDEN * 2) + ((kc * 64 + 16 * lhi) ^ ((row & 7) << 4));
                a[m] = *(const bf16x8*)(hb + byteoff);
            }
            #pragma unroll
            for (int n = 0; n < 4; ++n) {
                int col = w * 64 + 16 * n + llo;
                b[n] = *(const bf16x8*)(W2T + col * HIDDEN + kc * 32 + lhi * 8);
            }
            #pragma unroll
            for (int m = 0; m < 4; ++m)
                #pragma unroll
                for (int n = 0; n < 4; ++n)
                    acc[m][n] = __builtin_amdgcn_mfma_f32_16x16x32_bf16(a[m], b[n], acc[m][n], 0, 0, 0);
        }
    }
    __syncthreads();   // done reading h_lds

    // ---- store relu(M) bf16 into h_lds (swizzled) ----
    {
        char* hb = (char*)h_lds;
        #pragma unroll
        for (int m = 0; m < 4; ++m)
            #pragma unroll
            for (int n = 0; n < 4; ++n) {
                int col = w * 64 + 16 * n + llo;
                #pragma unroll
                for (int r = 0; r < 4; ++r) {
                    int row = 16 * m + 4 * lhi + r;
                    float v = fmaxf(acc[m][n][r], 0.0f);
                    int byteoff = row * (HIDDEN * 2) + ((col * 2) ^ ((row & 7) << 4));
                    *(__bf16*)(hb + byteoff) = (__bf16)v;
                }
            }
    }
    __syncthreads();

    // ---- write pair table: thread owns column c=t ----
    {
        const char* hb = (const char*)h_lds;
        const int c = t;
        for (int r = 0; r < TE; ++r) {
            unsigned short m16 = *(const unsigned short*)(hb + r * (HIDDEN * 2) + ((2 * c) ^ ((r & 7) << 4)));
            int i = eb + r;
            tab16[((size_t)i * HIDDEN + c) * 2] = m16;            // lo of pair[i]
            if (i > 0)
                tab16[((size_t)(i - 1) * HIDDEN + c) * 2 + 1] = m16; // hi of pair[i-1]
        }
    }
}

// Main: per edge, D -> lerp table -> * X[src] -> run-length reduced atomic add.
// Block = 256 threads, 64 edges; thread t owns output column c=t.
__global__ __launch_bounds__(256)
void cfconv_gather(const float* __restrict__ X,
                   const float* __restrict__ R,
                   const unsigned int* __restrict__ tab,
                   const int* __restrict__ src,
                   const int* __restrict__ dest,
                   float* __restrict__ out,
                   float scale, int Tm2) {
    __shared__ float Dl[TE];
    __shared__ int srcl[TE];
    __shared__ int destl[TE];

    const int t = threadIdx.x;
    // XCD-aware swizzle: 4096 blocks, 8 XCDs -> contiguous 512-tile chunk per XCD
    const int orig = blockIdx.x;
    const int cpx = gridDim.x >> 3;
    const int wg = (orig & 7) * cpx + (orig >> 3);
    const int eb = wg * TE;

    if (t < TE) {
        int e = eb + t;
        int s = src[e], d = dest[e];
        srcl[t] = s;
        destl[t] = d;
        float dx = R[s * 3 + 0] - R[d * 3 + 0];
        float dy = R[s * 3 + 1] - R[d * 3 + 1];
        float dz = R[s * 3 + 2] - R[d * 3 + 2];
        Dl[t] = dx * dx + dy * dy + dz * dz;
    }
    __syncthreads();

    const int c = t;
    float racc = 0.0f;
    int dprev = __builtin_amdgcn_readfirstlane(destl[0]);
    #pragma unroll 8
    for (int r = 0; r < TE; ++r) {
        int d = __builtin_amdgcn_readfirstlane(destl[r]);
        int s = __builtin_amdgcn_readfirstlane(srcl[r]);
        float u = Dl[r] * scale;
        int i0 = (int)u;
        i0 = min(i0, Tm2);
        float frac = u - (float)i0;
        unsigned pair = tab[(size_t)i0 * HIDDEN + c];
        union { unsigned u; float f; } lo, hi;
        lo.u = pair << 16;             // bf16 lo -> f32
        hi.u = pair & 0xffff0000u;     // bf16 hi -> f32
        float m = lo.f + frac * (hi.f - lo.f);
        float x = X[(size_t)s * HIDDEN + c];
        if (d != dprev) {
            unsafeAtomicAdd(out + (size_t)dprev * HIDDEN + c, racc);
            racc = 0.0f;
            dprev = d;
        }
        racc += m * x;
    }
    unsafeAtomicAdd(out + (size_t)dprev * HIDDEN + c, racc);
}

extern "C" void kernel_launch(void* const* d_in, const int* in_sizes, int n_in,
                              void* d_out, int out_size, void* d_ws, size_t ws_size,
                              hipStream_t stream) {
    const float* X  = (const float*)d_in[0];
    const float* R  = (const float*)d_in[1];
    const float* W1 = (const float*)d_in[2];
    const float* W2 = (const float*)d_in[3];
    const float* mu = (const float*)d_in[4];
    const int* src  = (const int*)d_in[5];
    const int* dest = (const int*)d_in[6];
    float* out = (float*)d_out;

    // workspace layout: W1T bf16 | W2T bf16 | pair table u32[T*256]
    unsigned short* W1T = (unsigned short*)d_ws;
    unsigned short* W2T = W1T + NB * HIDDEN;
    unsigned int*   tab = (unsigned int*)(W2T + HIDDEN * HIDDEN);

    const size_t fixed = (size_t)(NB * HIDDEN + HIDDEN * HIDDEN) * 2;
    int T = 2048;
    if (ws_size > 0) {
        while (T > 64 && fixed + (size_t)T * HIDDEN * 4 > ws_size) T >>= 1;
    }
    const float scale = (float)(T - 1) / R2MAX;
    const float invScale = R2MAX / (float)(T - 1);

    hipMemsetAsync(d_out, 0, (size_t)out_size * sizeof(float), stream);

    cfconv_prep<<<(NB * HIDDEN + HIDDEN * HIDDEN + 255) / 256, 256, 0, stream>>>(W1, W2, W1T);

    cfconv_build<<<T / TE, 256, 0, stream>>>(W1T, W2T, mu, (unsigned short*)tab, invScale);

    cfconv_gather<<<E_TOTAL / TE, 256, 0, stream>>>(X, R, tab, src, dest, out,
                                                    scale, T - 2);
}